// Round 1
// baseline (1834.033 us; speedup 1.0000x reference)
//
#include <hip/hip_runtime.h>
#include <math.h>

#define Bb 2
#define Hh 8
#define Ss 512
#define Dd 64

typedef float floatx4 __attribute__((ext_vector_type(4)));

__device__ __forceinline__ float rfl(float x) {
    return __int_as_float(__builtin_amdgcn_readfirstlane(__float_as_int(x)));
}

// One wave (64 lanes) owns one q-row end-to-end.
// Phase 1 is TRANSPOSED: lane l owns k = 64*i + l and reads the whole
// 256 B row R[k,:] (16 float4 w/ immediate offsets), dotted against the
// q-row held in SGPRs (wave-uniform via readfirstlane). No cross-lane
// shuffles, no masked LDS stores in the hot loop -> pure load/fma stream.
// Scores land in the lane that owns k for the softmax phase (registers).
__global__ __launch_bounds__(256) void relattn_kernel(
    const float* __restrict__ Q, const float* __restrict__ Kmat,
    const float* __restrict__ V, const float* __restrict__ R,
    const int* __restrict__ mask, float* __restrict__ out,
    float* __restrict__ p_out)
{
    __shared__ float ssc_all[4][Ss];          // per-wave p broadcast buffer

    const int tid  = threadIdx.x;
    const int wave = tid >> 6;
    const int lane = tid & 63;
    float* ssc = ssc_all[wave];

    const int row = __builtin_amdgcn_readfirstlane(blockIdx.x * 4 + wave);
    const int q   = row & (Ss - 1);
    const int bh  = row >> 9;                 // b*H + h
    const int b   = bh >> 3;                  // H == 8

    // ---- q row into SGPRs (uniform across the wave) ----
    float qs[Dd];
    {
        const floatx4* Q4 = (const floatx4*)(Q + (size_t)row * Dd);
        #pragma unroll
        for (int t = 0; t < 16; ++t) {
            floatx4 v = Q4[t];
            qs[4*t+0] = rfl(v.x); qs[4*t+1] = rfl(v.y);
            qs[4*t+2] = rfl(v.z); qs[4*t+3] = rfl(v.w);
        }
    }

    // ---- mask loads issued early; they overlap phase 1 ----
    const int* mrow = mask + (size_t)(b * Ss + q) * Ss;
    int m[8];
    #pragma unroll
    for (int i = 0; i < 8; ++i) m[i] = mrow[lane + 64 * i];

    const float* Rrow = R    + (size_t)row * Ss * Dd;
    const float* Kbh  = Kmat + (size_t)bh  * Ss * Dd;
    const float* Vbh  = V    + (size_t)bh  * Ss * Dd;

    // ---- Phase 1: lane-local scores, s[i] for k = 64*i + lane ----
    float s[8];
    #pragma unroll
    for (int i = 0; i < 8; ++i) {
        const int k = 64 * i + lane;
        const floatx4* r4 = (const floatx4*)(Rrow + (size_t)k * Dd);
        const floatx4* k4 = (const floatx4*)(Kbh  + (size_t)k * Dd);
        float acc = 0.0f;
        #pragma unroll
        for (int t = 0; t < 16; ++t) {
            floatx4 rv = __builtin_nontemporal_load(r4 + t);
            floatx4 kv = k4[t];
            acc = fmaf(rv.x + kv.x, qs[4*t+0], acc);
            acc = fmaf(rv.y + kv.y, qs[4*t+1], acc);
            acc = fmaf(rv.z + kv.z, qs[4*t+2], acc);
            acc = fmaf(rv.w + kv.w, qs[4*t+3], acc);
        }
        s[i] = (m[i] == 0) ? -1e9f : acc * 0.125f;
    }

    // ---- Phase 2: masked softmax, fully in-register + wave shuffles ----
    float mx = s[0];
    #pragma unroll
    for (int i = 1; i < 8; ++i) mx = fmaxf(mx, s[i]);
    #pragma unroll
    for (int o = 1; o < 64; o <<= 1) mx = fmaxf(mx, __shfl_xor(mx, o));

    float e[8], sm = 0.0f;
    #pragma unroll
    for (int i = 0; i < 8; ++i) { e[i] = __expf(s[i] - mx); sm += e[i]; }
    #pragma unroll
    for (int o = 1; o < 64; o <<= 1) sm += __shfl_xor(sm, o);
    const float inv = 1.0f / sm;

    float* prow = p_out + (size_t)row * Ss;
    #pragma unroll
    for (int i = 0; i < 8; ++i) {
        float p = (m[i] == 0) ? 0.0f : e[i] * inv;
        prow[lane + 64 * i] = p;              // coalesced 256 B stores
        ssc[lane + 64 * i]  = p;              // 2-way bank alias: free
    }
    __builtin_amdgcn_wave_barrier();

    // ---- Phase 3: out[row][:] = p . V (V is L2-resident) ----
    const int j  = lane & 15;                 // d4-group: d = 4j..4j+3
    const int kg = lane >> 4;                 // k-subgroup 0..3

    floatx4 acc = {0.f, 0.f, 0.f, 0.f};
    #pragma unroll 4
    for (int k = kg; k < Ss; k += 4) {
        float pk = ssc[k];                    // group-broadcast, conflict-free
        floatx4 vv = *(const floatx4*)(Vbh + (size_t)k * Dd + j * 4);
        acc.x = fmaf(pk, vv.x, acc.x);
        acc.y = fmaf(pk, vv.y, acc.y);
        acc.z = fmaf(pk, vv.z, acc.z);
        acc.w = fmaf(pk, vv.w, acc.w);
    }
    #pragma unroll
    for (int o = 16; o <= 32; o <<= 1) {
        acc.x += __shfl_xor(acc.x, o);
        acc.y += __shfl_xor(acc.y, o);
        acc.z += __shfl_xor(acc.z, o);
        acc.w += __shfl_xor(acc.w, o);
    }
    if (kg == 0)
        *(floatx4*)(out + (size_t)row * Dd + j * 4) = acc;
}

extern "C" void kernel_launch(void* const* d_in, const int* in_sizes, int n_in,
                              void* d_out, int out_size, void* d_ws, size_t ws_size,
                              hipStream_t stream) {
    const float* Q    = (const float*)d_in[0];
    const float* K    = (const float*)d_in[1];
    const float* V    = (const float*)d_in[2];
    const float* R    = (const float*)d_in[3];
    const int*   mask = (const int*)d_in[4];

    float* out   = (float*)d_out;
    float* p_out = out + (size_t)Bb * Hh * Ss * Dd;   // tuple order: out, p_attn

    relattn_kernel<<<(Bb * Hh * Ss) / 4, 256, 0, stream>>>(Q, K, V, R, mask, out, p_out);
}